// Round 4
// baseline (702.398 us; speedup 1.0000x reference)
//
#include <hip/hip_runtime.h>
#include <hip/hip_bf16.h>

#define B_   64
#define N_   4096
#define NSTEPS 8

__device__ __forceinline__ float fast_sigmoid(float x) {
    return 1.0f / (1.0f + __expf(-x));
}
__device__ __forceinline__ float fast_tanh(float x) {
    // 1 - 2/(exp(2x)+1); correct limits at +/-inf
    return 1.0f - 2.0f / (1.0f + __expf(2.0f * x));
}

// ---------------------------------------------------------------------------
// Kernel 1: UGRNN recurrence. One thread per token (b,n).
// __launch_bounds__(256,2): 256-VGPR budget so the ~110 live regs never
// spill (R2's (256,4)=128 cap caused scratch spills: WRITE_SIZE 16->33 MB).
// Sequential accumulator passes keep peak live floats ~80.
// Writes h transposed: h_t[(n*16+u)*64 + b]  (i-major, b-minor, coalesced).
// ---------------------------------------------------------------------------
__global__ __launch_bounds__(256, 2) void ugrnn_recurrence(
    const float* __restrict__ inputs,
    const float* __restrict__ Wn, const float* __restrict__ Wg,
    const float* __restrict__ Ug, const float* __restrict__ bg,
    const float* __restrict__ Wc, const float* __restrict__ Uc,
    const float* __restrict__ bc, const float* __restrict__ We,
    const float* __restrict__ be, float* __restrict__ h_t)
{
    int t = blockIdx.x * 256 + threadIdx.x;
    int b = t & 63;
    int n = t >> 6;

    // 34 floats per token, 8B-aligned -> 17 float2 gathers
    const float2* ip2 = (const float2*)(inputs + (size_t)(b * N_ + n) * 34);
    float tmp[34];
#pragma unroll
    for (int j = 0; j < 17; ++j) {
        float2 v = ip2[j];
        tmp[2 * j] = v.x;
        tmp[2 * j + 1] = v.y;
    }
    float h0 = tmp[0];
    float e0 = tmp[33];

    // m = neigh @ Wn   (32x16)
    float m[16];
#pragma unroll
    for (int u = 0; u < 16; ++u) m[u] = 0.0f;
#pragma unroll
    for (int k = 0; k < 32; ++k) {
        float xk = tmp[1 + k];
#pragma unroll
        for (int u = 0; u < 16; ++u) m[u] += xk * Wn[k * 16 + u];
    }

    float h[16], e[16];
#pragma unroll
    for (int u = 0; u < 16; ++u) { h[u] = h0; e[u] = e0; }

#pragma unroll 1   // keep I-footprint small
    for (int step = 0; step < NSTEPS; ++step) {
        float x[16];
#pragma unroll
        for (int u = 0; u < 16; ++u) x[u] = m[u] + e[u];
        // e dead until pass 3 rewrites it

        // ---- pass 1: g = sigmoid(x@Wg + h@Ug + bg) ----
        float g[16];
#pragma unroll
        for (int u = 0; u < 16; ++u) g[u] = bg[u];
#pragma unroll
        for (int k = 0; k < 16; ++k) {
            float xk = x[k], hk = h[k];
#pragma unroll
            for (int u = 0; u < 16; ++u) {
                g[u] += xk * Wg[k * 16 + u];
                g[u] += hk * Ug[k * 16 + u];
            }
        }
#pragma unroll
        for (int u = 0; u < 16; ++u) g[u] = fast_sigmoid(g[u]);

        // ---- pass 2: c = tanh(x@Wc + h@Uc + bc); h = c + g*(h-c) ----
        float c[16];
#pragma unroll
        for (int u = 0; u < 16; ++u) c[u] = bc[u];
#pragma unroll
        for (int k = 0; k < 16; ++k) {
            float xk = x[k], hk = h[k];
#pragma unroll
            for (int u = 0; u < 16; ++u) {
                c[u] += xk * Wc[k * 16 + u];
                c[u] += hk * Uc[k * 16 + u];
            }
        }
#pragma unroll
        for (int u = 0; u < 16; ++u) {
            float cv = fast_tanh(c[u]);
            h[u] = cv + g[u] * (h[u] - cv);
        }

        // ---- pass 3: e = tanh(x@We + be) ----
#pragma unroll
        for (int u = 0; u < 16; ++u) e[u] = be[u];
#pragma unroll
        for (int k = 0; k < 16; ++k) {
            float xk = x[k];
#pragma unroll
            for (int u = 0; u < 16; ++u) e[u] += xk * We[k * 16 + u];
        }
#pragma unroll
        for (int u = 0; u < 16; ++u) e[u] = fast_tanh(e[u]);
    }

    float* hp = h_t + (size_t)(n * 16) * 64 + b;
#pragma unroll
    for (int u = 0; u < 16; ++u) hp[u * 64] = h[u];
}

// ---------------------------------------------------------------------------
// Kernel 2-init: out1[b][j] = b1[j]  (atomic targets start at bias)
// ---------------------------------------------------------------------------
__global__ __launch_bounds__(256) void init_out1(
    const float* __restrict__ b1, float* __restrict__ out1)
{
    int idx = blockIdx.x * 256 + threadIdx.x;   // grid 64 -> 16384
    out1[idx] = b1[idx & 255];
}

// ---------------------------------------------------------------------------
// Kernel 2a: split-K FC1.  out1[b][j] += sum_i h_t[i][b] * W1[i][j]
// grid 512 x 256; block owns 128 i-rows (2 chunks of 64 staged in LDS).
// COVERAGE (fixed from R3): wave w owns b in [16w,16w+16) and ALL 256
// columns via 4-way j-register-blocking: lane's columns are 4*lane..4*lane+3
// (W1 row read as one coalesced float4 per lane). Each broadcast
// ds_read_b128 of h (16 b values) is reused across the 4 columns.
// acc[4][16] = 64 floats fits the (256,2) 256-VGPR budget without spill.
// ---------------------------------------------------------------------------
__global__ __launch_bounds__(256, 2) void fc1_splitk(
    const float* __restrict__ h_t, const float* __restrict__ W1,
    float* __restrict__ out1)
{
    __shared__ float hs[64 * 64];   // 16 KB: hs[i][b]
    int lane = threadIdx.x & 63;
    int wave = threadIdx.x >> 6;
    int b0 = wave * 16;
    int i0 = blockIdx.x * 128;

    float acc[4][16];               // [j-sub][b-sub]
#pragma unroll
    for (int k = 0; k < 4; ++k)
#pragma unroll
        for (int cc = 0; cc < 16; ++cc) acc[k][cc] = 0.0f;

    for (int s = 0; s < 2; ++s) {
        int ibase = i0 + s * 64;
        __syncthreads();
        const float4* src = (const float4*)(h_t + (size_t)ibase * 64);
        float4* dst = (float4*)hs;
#pragma unroll
        for (int r = 0; r < 4; ++r)
            dst[threadIdx.x + r * 256] = src[threadIdx.x + r * 256];
        __syncthreads();

#pragma unroll 2
        for (int i = 0; i < 64; ++i) {
            // lane's 4 columns: one coalesced 16B load of the W1 row
            float4 wv = ((const float4*)(W1 + (size_t)(ibase + i) * 256))[lane];
            const float4* hp = (const float4*)&hs[i * 64 + b0]; // wave-uniform
#pragma unroll
            for (int c4 = 0; c4 < 4; ++c4) {
                float4 h4 = hp[c4];                  // broadcast ds_read_b128
#pragma unroll
                for (int q = 0; q < 4; ++q) {
                    float hv = (q == 0) ? h4.x : (q == 1) ? h4.y
                             : (q == 2) ? h4.z : h4.w;
                    acc[0][c4 * 4 + q] += hv * wv.x;
                    acc[1][c4 * 4 + q] += hv * wv.y;
                    acc[2][c4 * 4 + q] += hv * wv.z;
                    acc[3][c4 * 4 + q] += hv * wv.w;
                }
            }
        }
    }

#pragma unroll 1
    for (int cc = 0; cc < 16; ++cc) {
#pragma unroll
        for (int k = 0; k < 4; ++k)
            atomicAdd(&out1[(b0 + cc) * 256 + 4 * lane + k], acc[k][cc]);
    }
}

// ---------------------------------------------------------------------------
// Kernel 2c: tail MLP + softmax. One block per batch row b.
// ---------------------------------------------------------------------------
__global__ __launch_bounds__(64) void mlp_tail(
    const float* __restrict__ out1, const float* __restrict__ W2,
    const float* __restrict__ b2, const float* __restrict__ W3,
    const float* __restrict__ b3, float* __restrict__ out)
{
    __shared__ float x1[256];
    __shared__ float x2[32];
    __shared__ float lg[2];
    int b = blockIdx.x, tid = threadIdx.x;

#pragma unroll
    for (int r = 0; r < 4; ++r) {
        float v = out1[b * 256 + tid * 4 + r];
        x1[tid * 4 + r] = fmaxf(v, 0.0f);
    }
    __syncthreads();

    if (tid < 32) {
        float s = b2[tid];
#pragma unroll 8
        for (int k = 0; k < 256; ++k) s += x1[k] * W2[k * 32 + tid];
        x2[tid] = fmaxf(s, 0.0f);
    }
    __syncthreads();

    if (tid < 2) {
        float s = b3[tid];
#pragma unroll
        for (int k = 0; k < 32; ++k) s += x2[k] * W3[k * 2 + tid];
        lg[tid] = s;
    }
    __syncthreads();

    if (tid == 0) {
        float mx = fmaxf(lg[0], lg[1]);
        float e0 = __expf(lg[0] - mx), e1 = __expf(lg[1] - mx);
        float inv = 1.0f / (e0 + e1);
        out[b * 2 + 0] = e0 * inv;
        out[b * 2 + 1] = e1 * inv;
    }
}

// ---------------------------------------------------------------------------
extern "C" void kernel_launch(void* const* d_in, const int* in_sizes, int n_in,
                              void* d_out, int out_size, void* d_ws, size_t ws_size,
                              hipStream_t stream) {
    const float* inputs = (const float*)d_in[0];
    const float* Wn = (const float*)d_in[1];
    const float* Wg = (const float*)d_in[2];
    const float* Ug = (const float*)d_in[3];
    const float* bg = (const float*)d_in[4];
    const float* Wc = (const float*)d_in[5];
    const float* Uc = (const float*)d_in[6];
    const float* bc = (const float*)d_in[7];
    const float* We = (const float*)d_in[8];
    const float* be = (const float*)d_in[9];
    const float* W1 = (const float*)d_in[10];
    const float* b1 = (const float*)d_in[11];
    const float* W2 = (const float*)d_in[12];
    const float* b2 = (const float*)d_in[13];
    const float* W3 = (const float*)d_in[14];
    const float* b3 = (const float*)d_in[15];
    float* out = (float*)d_out;

    // workspace layout
    float* h_t  = (float*)d_ws;                                   // 65536*64 f32 = 16 MB
    float* out1 = (float*)((char*)d_ws + (size_t)65536 * 64 * 4); // 64*256 f32 = 64 KB

    ugrnn_recurrence<<<1024, 256, 0, stream>>>(inputs, Wn, Wg, Ug, bg, Wc, Uc, bc,
                                               We, be, h_t);
    init_out1<<<64, 256, 0, stream>>>(b1, out1);
    fc1_splitk<<<512, 256, 0, stream>>>(h_t, W1, out1);
    mlp_tail<<<64, 64, 0, stream>>>(out1, W2, b2, W3, b3, out);
}

// Round 5
// 560.609 us; speedup vs baseline: 1.2529x; 1.2529x over previous
//
#include <hip/hip_runtime.h>
#include <hip/hip_bf16.h>

#define B_   64
#define N_   4096
#define NSTEPS 8

__device__ __forceinline__ float fast_sigmoid(float x) {
    return 1.0f / (1.0f + __expf(-x));
}
__device__ __forceinline__ float fast_tanh(float x) {
    // 1 - 2/(exp(2x)+1); correct limits at +/-inf
    return 1.0f - 2.0f / (1.0f + __expf(2.0f * x));
}

// ---------------------------------------------------------------------------
// Kernel 1: UGRNN recurrence. One thread per token (b,n).
// __launch_bounds__(256,3): 168-VGPR cap; peak live ~100 floats (sequential
// accumulator passes), so no spill expected. WRITE_SIZE==16384 KB is the
// no-spill check; if it exceeds that, the cap bites and we revert to (256,2).
// Writes h transposed: h_t[(n*16+u)*64 + b]  (i-major, b-minor, coalesced).
// NOTE: no dynamic indexing of register arrays anywhere (scratch demotion
// was R4's fc1 failure: 235 MB scratch writes).
// ---------------------------------------------------------------------------
__global__ __launch_bounds__(256, 3) void ugrnn_recurrence(
    const float* __restrict__ inputs,
    const float* __restrict__ Wn, const float* __restrict__ Wg,
    const float* __restrict__ Ug, const float* __restrict__ bg,
    const float* __restrict__ Wc, const float* __restrict__ Uc,
    const float* __restrict__ bc, const float* __restrict__ We,
    const float* __restrict__ be, float* __restrict__ h_t)
{
    int t = blockIdx.x * 256 + threadIdx.x;
    int b = t & 63;
    int n = t >> 6;

    // 34 floats per token, 8B-aligned -> 17 float2 gathers
    const float2* ip2 = (const float2*)(inputs + (size_t)(b * N_ + n) * 34);
    float tmp[34];
#pragma unroll
    for (int j = 0; j < 17; ++j) {
        float2 v = ip2[j];
        tmp[2 * j] = v.x;
        tmp[2 * j + 1] = v.y;
    }
    float h0 = tmp[0];
    float e0 = tmp[33];

    // m = neigh @ Wn   (32x16)
    float m[16];
#pragma unroll
    for (int u = 0; u < 16; ++u) m[u] = 0.0f;
#pragma unroll
    for (int k = 0; k < 32; ++k) {
        float xk = tmp[1 + k];
#pragma unroll
        for (int u = 0; u < 16; ++u) m[u] += xk * Wn[k * 16 + u];
    }

    float h[16], e[16];
#pragma unroll
    for (int u = 0; u < 16; ++u) { h[u] = h0; e[u] = e0; }

#pragma unroll 1   // keep I-footprint small
    for (int step = 0; step < NSTEPS; ++step) {
        float x[16];
#pragma unroll
        for (int u = 0; u < 16; ++u) x[u] = m[u] + e[u];
        // e dead until pass 3 rewrites it

        // ---- pass 1: g = sigmoid(x@Wg + h@Ug + bg) ----
        float g[16];
#pragma unroll
        for (int u = 0; u < 16; ++u) g[u] = bg[u];
#pragma unroll
        for (int k = 0; k < 16; ++k) {
            float xk = x[k], hk = h[k];
#pragma unroll
            for (int u = 0; u < 16; ++u) {
                g[u] += xk * Wg[k * 16 + u];
                g[u] += hk * Ug[k * 16 + u];
            }
        }
#pragma unroll
        for (int u = 0; u < 16; ++u) g[u] = fast_sigmoid(g[u]);

        // ---- pass 2: c = tanh(x@Wc + h@Uc + bc); h = c + g*(h-c) ----
        float c[16];
#pragma unroll
        for (int u = 0; u < 16; ++u) c[u] = bc[u];
#pragma unroll
        for (int k = 0; k < 16; ++k) {
            float xk = x[k], hk = h[k];
#pragma unroll
            for (int u = 0; u < 16; ++u) {
                c[u] += xk * Wc[k * 16 + u];
                c[u] += hk * Uc[k * 16 + u];
            }
        }
#pragma unroll
        for (int u = 0; u < 16; ++u) {
            float cv = fast_tanh(c[u]);
            h[u] = cv + g[u] * (h[u] - cv);
        }

        // ---- pass 3: e = tanh(x@We + be) ----
#pragma unroll
        for (int u = 0; u < 16; ++u) e[u] = be[u];
#pragma unroll
        for (int k = 0; k < 16; ++k) {
            float xk = x[k];
#pragma unroll
            for (int u = 0; u < 16; ++u) e[u] += xk * We[k * 16 + u];
        }
#pragma unroll
        for (int u = 0; u < 16; ++u) e[u] = fast_tanh(e[u]);
    }

    float* hp = h_t + (size_t)(n * 16) * 64 + b;
#pragma unroll
    for (int u = 0; u < 16; ++u) hp[u * 64] = h[u];
}

// ---------------------------------------------------------------------------
// Kernel 2-init: out1[b][j] = b1[j]  (atomic targets start at bias)
// ---------------------------------------------------------------------------
__global__ __launch_bounds__(256) void init_out1(
    const float* __restrict__ b1, float* __restrict__ out1)
{
    int idx = blockIdx.x * 256 + threadIdx.x;   // grid 64 -> 16384
    out1[idx] = b1[idx & 255];
}

// ---------------------------------------------------------------------------
// Kernel 2a: split-K FC1.  out1[b][j] += sum_i h_t[i][b] * W1[i][j]
// grid 256 x 256; block owns 256 i-rows (4 chunks of 64 staged in LDS).
// Wave w owns b in [16w,16w+16) and ALL 256 columns, 4-way j-blocked:
// lane's columns 4*lane..4*lane+3 (one coalesced float4 W1 load per lane).
// acc[4][16]=64 floats in VGPRs. EPILOGUE FULLY UNROLLED — R4's
// `#pragma unroll 1` over a register-array index demoted acc to scratch
// (WRITE_SIZE 235 MB, 326 us). Constant indices keep it in registers.
// ---------------------------------------------------------------------------
__global__ __launch_bounds__(256, 2) void fc1_splitk(
    const float* __restrict__ h_t, const float* __restrict__ W1,
    float* __restrict__ out1)
{
    __shared__ float hs[64 * 64];   // 16 KB: hs[i][b]
    int lane = threadIdx.x & 63;
    int wave = threadIdx.x >> 6;
    int b0 = wave * 16;
    int i0 = blockIdx.x * 256;

    float acc[4][16];               // [j-sub][b-sub]
#pragma unroll
    for (int k = 0; k < 4; ++k)
#pragma unroll
        for (int cc = 0; cc < 16; ++cc) acc[k][cc] = 0.0f;

    for (int s = 0; s < 4; ++s) {
        int ibase = i0 + s * 64;
        __syncthreads();
        const float4* src = (const float4*)(h_t + (size_t)ibase * 64);
        float4* dst = (float4*)hs;
#pragma unroll
        for (int r = 0; r < 4; ++r)
            dst[threadIdx.x + r * 256] = src[threadIdx.x + r * 256];
        __syncthreads();

#pragma unroll 2
        for (int i = 0; i < 64; ++i) {
            // lane's 4 columns: one coalesced 16B load of the W1 row
            float4 wv = ((const float4*)(W1 + (size_t)(ibase + i) * 256))[lane];
            const float4* hp = (const float4*)&hs[i * 64 + b0]; // wave-uniform
#pragma unroll
            for (int c4 = 0; c4 < 4; ++c4) {
                float4 h4 = hp[c4];                  // broadcast ds_read_b128
#pragma unroll
                for (int q = 0; q < 4; ++q) {
                    float hv = (q == 0) ? h4.x : (q == 1) ? h4.y
                             : (q == 2) ? h4.z : h4.w;
                    acc[0][c4 * 4 + q] += hv * wv.x;
                    acc[1][c4 * 4 + q] += hv * wv.y;
                    acc[2][c4 * 4 + q] += hv * wv.z;
                    acc[3][c4 * 4 + q] += hv * wv.w;
                }
            }
        }
    }

    // fully unrolled epilogue: constant indices into acc -> stays in VGPRs
#pragma unroll
    for (int cc = 0; cc < 16; ++cc) {
#pragma unroll
        for (int k = 0; k < 4; ++k)
            atomicAdd(&out1[(b0 + cc) * 256 + 4 * lane + k], acc[k][cc]);
    }
}

// ---------------------------------------------------------------------------
// Kernel 2c: tail MLP + softmax. One block per batch row b.
// ---------------------------------------------------------------------------
__global__ __launch_bounds__(64) void mlp_tail(
    const float* __restrict__ out1, const float* __restrict__ W2,
    const float* __restrict__ b2, const float* __restrict__ W3,
    const float* __restrict__ b3, float* __restrict__ out)
{
    __shared__ float x1[256];
    __shared__ float x2[32];
    __shared__ float lg[2];
    int b = blockIdx.x, tid = threadIdx.x;

#pragma unroll
    for (int r = 0; r < 4; ++r) {
        float v = out1[b * 256 + tid * 4 + r];
        x1[tid * 4 + r] = fmaxf(v, 0.0f);
    }
    __syncthreads();

    if (tid < 32) {
        float s = b2[tid];
#pragma unroll 8
        for (int k = 0; k < 256; ++k) s += x1[k] * W2[k * 32 + tid];
        x2[tid] = fmaxf(s, 0.0f);
    }
    __syncthreads();

    if (tid < 2) {
        float s = b3[tid];
#pragma unroll
        for (int k = 0; k < 32; ++k) s += x2[k] * W3[k * 2 + tid];
        lg[tid] = s;
    }
    __syncthreads();

    if (tid == 0) {
        float mx = fmaxf(lg[0], lg[1]);
        float e0 = __expf(lg[0] - mx), e1 = __expf(lg[1] - mx);
        float inv = 1.0f / (e0 + e1);
        out[b * 2 + 0] = e0 * inv;
        out[b * 2 + 1] = e1 * inv;
    }
}

// ---------------------------------------------------------------------------
extern "C" void kernel_launch(void* const* d_in, const int* in_sizes, int n_in,
                              void* d_out, int out_size, void* d_ws, size_t ws_size,
                              hipStream_t stream) {
    const float* inputs = (const float*)d_in[0];
    const float* Wn = (const float*)d_in[1];
    const float* Wg = (const float*)d_in[2];
    const float* Ug = (const float*)d_in[3];
    const float* bg = (const float*)d_in[4];
    const float* Wc = (const float*)d_in[5];
    const float* Uc = (const float*)d_in[6];
    const float* bc = (const float*)d_in[7];
    const float* We = (const float*)d_in[8];
    const float* be = (const float*)d_in[9];
    const float* W1 = (const float*)d_in[10];
    const float* b1 = (const float*)d_in[11];
    const float* W2 = (const float*)d_in[12];
    const float* b2 = (const float*)d_in[13];
    const float* W3 = (const float*)d_in[14];
    const float* b3 = (const float*)d_in[15];
    float* out = (float*)d_out;

    // workspace layout
    float* h_t  = (float*)d_ws;                                   // 65536*64 f32 = 16 MB
    float* out1 = (float*)((char*)d_ws + (size_t)65536 * 64 * 4); // 64*256 f32 = 64 KB

    ugrnn_recurrence<<<1024, 256, 0, stream>>>(inputs, Wn, Wg, Ug, bg, Wc, Uc, bc,
                                               We, be, h_t);
    init_out1<<<64, 256, 0, stream>>>(b1, out1);
    fc1_splitk<<<256, 256, 0, stream>>>(h_t, W1, out1);
    mlp_tail<<<64, 64, 0, stream>>>(out1, W2, b2, W3, b3, out);
}